// Round 15
// baseline (479.968 us; speedup 1.0000x reference)
//
#include <hip/hip_runtime.h>
#include <hip/hip_fp16.h>

#define D   128
#define NN  40000
#define NB  625      // dst buckets per relation (64 nodes each)
#define GS  64       // edge slices per relation (hist + fill)

typedef unsigned long long ull;
typedef __attribute__((ext_vector_type(8))) _Float16 f16x8;
typedef __attribute__((ext_vector_type(4))) float f32x4;

struct Ptrs { const int* src[4]; const int* dst[4]; const float* w[4]; };

// ---- convert f32 table -> fp16 interleaved [node][128] ---------------------
__global__ __launch_bounds__(256) void conv_kernel(
    const float* __restrict__ in, __half* __restrict__ out, int n8)
{
    int i = blockIdx.x * 256 + threadIdx.x;
    if (i >= n8) return;
    const float4* a = (const float4*)in + (size_t)i * 2;
    float4 v0 = a[0], v1 = a[1];
    __half2 pack[4];
    pack[0] = __floats2half2_rn(v0.x, v0.y);
    pack[1] = __floats2half2_rn(v0.z, v0.w);
    pack[2] = __floats2half2_rn(v1.x, v1.y);
    pack[3] = __floats2half2_rn(v1.z, v1.w);
    ((float4*)out)[i] = *(float4*)pack;
}

// ---- pack W [128][128] f32 -> per-fragment fp16 [kt(4)][ct(8)][lane(64)][8]
__global__ __launch_bounds__(256) void wpack_kernel(
    const float* __restrict__ W0, const float* __restrict__ W1,
    const float* __restrict__ W2, const float* __restrict__ W3,
    __half* __restrict__ wp)
{
    int t = blockIdx.x * 256 + threadIdx.x;   // rel*2048 + idx
    int rel = t >> 11;
    int idx = t & 2047;
    int lane = idx & 63;
    int ct = (idx >> 6) & 7;
    int kt = idx >> 9;
    const float* W = rel == 0 ? W0 : rel == 1 ? W1 : rel == 2 ? W2 : W3;
    int k0 = kt * 32 + (lane >> 4) * 8;
    int col = ct * 16 + (lane & 15);
    __half tmp[8];
#pragma unroll
    for (int j = 0; j < 8; ++j)
        tmp[j] = __float2half_rn(W[(size_t)(k0 + j) * D + col]);
    *(float4*)(wp + (size_t)t * 8) = *(float4*)tmp;
}

// ---- hist (fused bcnt): full-N LDS src histogram + dst bucket counts -------
__global__ __launch_bounds__(1024) void hist_kernel(
    Ptrs p, __half* __restrict__ histo16, int* __restrict__ cnt_store, int E)
{
    __shared__ float hist[NN];
    __shared__ int cnt[NB];
    const int bx  = blockIdx.x;         // rel*GS + rep
    const int rel = bx >> 6;
    const int rep = bx & (GS - 1);
    const int tid = threadIdx.x;

    for (int i = tid; i < NN; i += 1024) hist[i] = 0.f;
    for (int i = tid; i < NB; i += 1024) cnt[i] = 0;
    __syncthreads();

    const int es  = (E + GS - 1) / GS;
    const int beg = rep * es;
    const int end = min(beg + es, E);
    const int* srcp = p.src[rel];
    const int* dstp = p.dst[rel];
    const float* w = p.w[rel];
    for (int e = beg + tid; e < end; e += 1024) {
        atomicAdd(&hist[__builtin_nontemporal_load(srcp + e)],
                  __builtin_nontemporal_load(w + e));
        atomicAdd(&cnt[__builtin_nontemporal_load(dstp + e) >> 6], 1);
    }
    __syncthreads();

    __half2* outp = (__half2*)(histo16 + (size_t)bx * NN);
    for (int i = tid; i < NN / 2; i += 1024)
        outp[i] = __floats2half2_rn(hist[2 * i], hist[2 * i + 1]);
    for (int b = tid; b < NB; b += 1024)
        cnt_store[((size_t)(rel * NB + b)) * GS + rep] = cnt[b];
}

__global__ __launch_bounds__(256) void reduce_kernel(
    const __half* __restrict__ histo16, float* __restrict__ rdego, int total)
{
    int i = blockIdx.x * 256 + threadIdx.x;     // i = rel*NN + node
    if (i >= total) return;
    int rel = i / NN;
    int node = i - rel * NN;
    const __half* bp = histo16 + (size_t)rel * GS * NN + node;
    float v = 0.f;
#pragma unroll
    for (int r = 0; r < GS; ++r) v += __half2float(bp[(size_t)r * NN]);
    rdego[i] = rsqrtf(v);
}

// ---- 3-kernel scan over 4*NB*GS = 160000 counts ----------------------------
__device__ inline int block_excl_scan(int v, int tid) {
    __shared__ int wsum[16];
    int lane = tid & 63, wid = tid >> 6;
    int x = v;
#pragma unroll
    for (int off = 1; off < 64; off <<= 1) {
        int y = __shfl_up(x, off, 64);
        if (lane >= off) x += y;
    }
    if (lane == 63) wsum[wid] = x;
    __syncthreads();
    if (wid == 0) {
        int y = (lane < 16) ? wsum[lane] : 0;
#pragma unroll
        for (int off = 1; off < 16; off <<= 1) {
            int t = __shfl_up(y, off, 64);
            if (lane >= off) y += t;
        }
        if (lane < 16) wsum[lane] = y;
    }
    __syncthreads();
    int woff = wid ? wsum[wid - 1] : 0;
    return woff + x - v;
}

__global__ __launch_bounds__(1024) void scan1_kernel(
    const int* __restrict__ cnt_store, int* __restrict__ scanex,
    int* __restrict__ bsum, int total)
{
    int tid = threadIdx.x;
    int i = blockIdx.x * 1024 + tid;
    int v = (i < total) ? cnt_store[i] : 0;
    int excl = block_excl_scan(v, tid);
    if (i < total) scanex[i] = excl;
    if (tid == 1023) bsum[blockIdx.x] = excl + v;
}

__global__ __launch_bounds__(1024) void scan2_kernel(int* __restrict__ bsum, int nb)
{
    int tid = threadIdx.x;
    int v = (tid < nb) ? bsum[tid] : 0;
    int excl = block_excl_scan(v, tid);
    if (tid < nb) bsum[tid] = excl;
}

__global__ __launch_bounds__(256) void scan3_kernel(
    const int* __restrict__ scanex, const int* __restrict__ bsum,
    int* __restrict__ cursor_base, int* __restrict__ bucket_ptr,
    int total, int E)
{
    int i = blockIdx.x * 256 + threadIdx.x;
    if (i >= total) return;
    int v = scanex[i] + bsum[i >> 10];
    int rel = i / (NB * GS);
    int rem = i - rel * (NB * GS);
    int b = rem / GS, rep = rem - b * GS;
    int local = v - rel * E;            // each relation has exactly E edges
    cursor_base[i] = local;
    if (rep == 0) bucket_ptr[rel * (NB + 1) + b] = local;
    if (rem == 0) bucket_ptr[rel * (NB + 1) + NB] = E;
}

// ---- fill4: all relations; coarse bucket sort; LDS cursors -----------------
__global__ __launch_bounds__(512) void fill4_kernel(
    Ptrs p, const int* __restrict__ cursor_base,
    ull* __restrict__ csr8, int E)
{
    __shared__ int lcur[NB];
    const int rel = blockIdx.x / GS;
    const int rep = blockIdx.x - rel * GS;
    const int tid = threadIdx.x;
    const int* cb = cursor_base + (size_t)rel * NB * GS;
    for (int b = tid; b < NB; b += 512)
        lcur[b] = cb[(size_t)b * GS + rep];
    __syncthreads();
    const int es  = (E + GS - 1) / GS;
    const int beg = rep * es;
    const int end = min(beg + es, E);
    const int* src = p.src[rel];
    const int* dst = p.dst[rel];
    const float* w = p.w[rel];
    ull* c8 = csr8 + (size_t)rel * E;
    for (int e = beg + tid; e < end; e += 512) {
        int s = __builtin_nontemporal_load(src + e);
        int d = __builtin_nontemporal_load(dst + e);
        float we = __builtin_nontemporal_load(w + e);
        int pos = atomicAdd(&lcur[d >> 6], 1);
        ull rec = (ull)(unsigned)(s | ((d & 63) << 16)) |
                  ((ull)__float_as_uint(we) << 32);
        __builtin_nontemporal_store(rec, c8 + pos);
    }
}

// ---- sort24: all relations; bucket -> exact per-dst CSR; bake wn; 4B recs --
__global__ __launch_bounds__(256) void sort24_kernel(
    const int* __restrict__ bucket_ptr, const ull* __restrict__ csr8,
    const float* __restrict__ rdego, unsigned* __restrict__ csr2u,
    int* __restrict__ row_ptr, int E)
{
    __shared__ int cnt[64];
    __shared__ int cur[64];
    __shared__ float swsum[64];
    const int rel = blockIdx.x / NB;
    const int b   = blockIdx.x - rel * NB;
    const int tid = threadIdx.x;
    const int* bp_r = bucket_ptr + rel * (NB + 1);
    const ull* c8 = csr8 + (size_t)rel * E;
    unsigned* c2 = csr2u + (size_t)rel * E;
    int* rp_r = row_ptr + rel * (NN + 1);
    const float* rd = rdego + (size_t)rel * NN;
    const int beg = bp_r[b];
    const int end = bp_r[b + 1];
    if (tid < 64) { cnt[tid] = 0; swsum[tid] = 0.f; }
    __syncthreads();
    for (int e = beg + tid; e < end; e += 256) {
        ull rec = __builtin_nontemporal_load(c8 + e);
        int j = (int)((rec >> 16) & 63);
        atomicAdd(&cnt[j], 1);
        atomicAdd(&swsum[j], __uint_as_float((unsigned)(rec >> 32)));
    }
    __syncthreads();
    if (tid < 64) {                      // wave 0: exclusive scan of 64 bins
        int v = cnt[tid];
        int x = v;
#pragma unroll
        for (int off = 1; off < 64; off <<= 1) {
            int y = __shfl_up(x, off, 64);
            if (tid >= off) x += y;
        }
        int start = beg + x - v;
        cur[tid] = start;
        rp_r[b * 64 + tid] = start;
        swsum[tid] = rsqrtf(swsum[tid]);
        if (b == 0 && tid == 0) rp_r[NN] = E;
    }
    __syncthreads();
    for (int e = beg + tid; e < end; e += 256) {
        ull rec = __builtin_nontemporal_load(c8 + e);
        int j = (int)((rec >> 16) & 63);
        int s = (int)(rec & 0xFFFF);
        float wn = __uint_as_float((unsigned)(rec >> 32)) * rd[s] * swsum[j];
        int pos = atomicAdd(&cur[j], 1);
        __builtin_nontemporal_store(
            (unsigned)s | ((unsigned)__half_as_ushort(__float2half_rn(wn)) << 16),
            c2 + pos);
    }
}

// ---- gather4: all relations; one wave/node; MLP=8 (2-deep unroll x 4 grp) --
__global__ __launch_bounds__(256) void gather4_kernel(
    const int* __restrict__ row_ptr, const unsigned* __restrict__ csr2u,
    const __half* __restrict__ h16com, const __half* __restrict__ h16pos,
    __half* __restrict__ agg16, int gBlocks, int E)
{
    int rel = blockIdx.x / gBlocks;
    int lb  = blockIdx.x - rel * gBlocks;
    int node = (lb * 256 + threadIdx.x) >> 6;
    int lane = threadIdx.x & 63;
    if (node >= NN) return;
    const int* rp = row_ptr + rel * (NN + 1);
    const unsigned* c2 = csr2u + (size_t)rel * E;
    const __half* h16 = (rel == 0 || rel == 3) ? h16com : h16pos;
    __half* agg = agg16 + (size_t)rel * NN * D;

    int beg = rp[node], end = rp[node + 1];
    const int g = lane >> 4, l16 = lane & 15;

    float acc[8] = {};
    int e = beg;
    // 2-deep unrolled: 8 rows in flight per wave
    for (; e + 8 <= end; e += 8) {
        unsigned rec0 = __builtin_nontemporal_load(c2 + e + g);
        unsigned rec1 = __builtin_nontemporal_load(c2 + e + 4 + g);
        int s0 = (int)(rec0 & 0xFFFF);
        int s1 = (int)(rec1 & 0xFFFF);
        f32x4 hv0 = ((const f32x4*)(h16 + (size_t)s0 * D))[l16];
        f32x4 hv1 = ((const f32x4*)(h16 + (size_t)s1 * D))[l16];
        float wn0 = __half2float(__ushort_as_half((unsigned short)(rec0 >> 16)));
        float wn1 = __half2float(__ushort_as_half((unsigned short)(rec1 >> 16)));
        __half2* hp0 = (__half2*)&hv0;
        __half2* hp1 = (__half2*)&hv1;
#pragma unroll
        for (int k = 0; k < 4; ++k) {
            float2 f0 = __half22float2(hp0[k]);
            float2 f1 = __half22float2(hp1[k]);
            acc[2 * k]     += wn0 * f0.x + wn1 * f1.x;
            acc[2 * k + 1] += wn0 * f0.y + wn1 * f1.y;
        }
    }
    // tail: 4-at-a-time with predication
    for (; e < end; e += 4) {
        int ee = e + g;
        int valid = ee < end;
        unsigned rec = __builtin_nontemporal_load(c2 + (valid ? ee : (end - 1)));
        int s = (int)(rec & 0xFFFF);
        float wn = valid ? __half2float(__ushort_as_half((unsigned short)(rec >> 16))) : 0.f;
        f32x4 hv4 = ((const f32x4*)(h16 + (size_t)s * D))[l16];
        __half2* hp = (__half2*)&hv4;
#pragma unroll
        for (int k = 0; k < 4; ++k) {
            float2 f = __half22float2(hp[k]);
            acc[2 * k]     += wn * f.x;
            acc[2 * k + 1] += wn * f.y;
        }
    }
#pragma unroll
    for (int k = 0; k < 8; ++k) {
        acc[k] += __shfl_xor(acc[k], 16, 64);
        acc[k] += __shfl_xor(acc[k], 32, 64);
    }
    if (g == 0) {
        __half2 pack[4];
        pack[0] = __floats2half2_rn(acc[0], acc[1]);
        pack[1] = __floats2half2_rn(acc[2], acc[3]);
        pack[2] = __floats2half2_rn(acc[4], acc[5]);
        pack[3] = __floats2half2_rn(acc[6], acc[7]);
        __builtin_nontemporal_store(*(f32x4*)pack,
                                    (f32x4*)(agg + (size_t)node * D) + l16);
    }
}

// ---- projmf: MFMA fp16 GEMM, both relations of an output half fused --------
__global__ __launch_bounds__(256) void projmf_kernel(
    const __half* __restrict__ aggA, const __half* __restrict__ wpA,
    const float* __restrict__ bA,
    const __half* __restrict__ aggB, const __half* __restrict__ wpB,
    const float* __restrict__ bB, float* __restrict__ outh)
{
    __shared__ char As[2][64 * 256];    // 2 x 16 KB, XOR-swizzled rows
    const int t = threadIdx.x;
    const int row0 = blockIdx.x * 64;

    for (int r2 = 0; r2 < 2; ++r2) {
        const float4* src = (const float4*)((r2 ? aggB : aggA) + (size_t)row0 * D);
        for (int i = t; i < 1024; i += 256) {
            int row = i >> 4, ch = i & 15;
            int byte = row * 256 + ch * 16;
            byte ^= (row & 7) << 4;
            *(float4*)(As[r2] + byte) = src[i];
        }
    }
    __syncthreads();

    const int wv = t >> 6, lane = t & 63;
    const int rbase = wv * 16;

    f16x8 aA[4], aB[4];
#pragma unroll
    for (int kt = 0; kt < 4; ++kt) {
        int row = rbase + (lane & 15);
        int byte = row * 256 + kt * 64 + (lane >> 4) * 16;
        byte ^= (row & 7) << 4;
        aA[kt] = *(const f16x8*)(As[0] + byte);
        aB[kt] = *(const f16x8*)(As[1] + byte);
    }

    f32x4 accA[8], accB[8];
#pragma unroll
    for (int i = 0; i < 8; ++i) {
        accA[i] = (f32x4){0.f, 0.f, 0.f, 0.f};
        accB[i] = (f32x4){0.f, 0.f, 0.f, 0.f};
    }

#pragma unroll
    for (int ct = 0; ct < 8; ++ct) {
#pragma unroll
        for (int kt = 0; kt < 4; ++kt) {
            f16x8 bfA = *(const f16x8*)(wpA + ((size_t)((kt * 8 + ct) * 64 + lane)) * 8);
            f16x8 bfB = *(const f16x8*)(wpB + ((size_t)((kt * 8 + ct) * 64 + lane)) * 8);
            accA[ct] = __builtin_amdgcn_mfma_f32_16x16x32_f16(aA[kt], bfA, accA[ct], 0, 0, 0);
            accB[ct] = __builtin_amdgcn_mfma_f32_16x16x32_f16(aB[kt], bfB, accB[ct], 0, 0, 0);
        }
    }

    // C/D layout: col = lane&15, row = (lane>>4)*4 + v
#pragma unroll
    for (int ct = 0; ct < 8; ++ct) {
        int col = ct * 16 + (lane & 15);
        float ba = bA[col], bb = bB[col];
#pragma unroll
        for (int v = 0; v < 4; ++v) {
            int row = row0 + rbase + (lane >> 4) * 4 + v;
            float r = 0.5f * (fmaxf(accA[ct][v] + ba, 0.f) +
                              fmaxf(accB[ct][v] + bb, 0.f));
            outh[(size_t)row * D + col] = r;
        }
    }
}

extern "C" void kernel_launch(void* const* d_in, const int* in_sizes, int n_in,
                              void* d_out, int out_size, void* d_ws, size_t ws_size,
                              hipStream_t stream) {
    const float* com_emb = (const float*)d_in[0];
    const float* pos_emb = (const float*)d_in[1];
    const int E = in_sizes[2];       // 1,000,000
    const int N = NN;

    float* out = (float*)d_out;
    float* out_com = out;
    float* out_pos = out + (size_t)N * D;

    // relation order: 0=cflow(com->com) 1=supply(pos->com) 2=pflow(pos->pos) 3=demand(com->pos)
    Ptrs ptrs;
    ptrs.src[0] = (const int*)d_in[8];  ptrs.dst[0] = (const int*)d_in[9];  ptrs.w[0] = (const float*)d_in[10];
    ptrs.src[1] = (const int*)d_in[5];  ptrs.dst[1] = (const int*)d_in[6];  ptrs.w[1] = (const float*)d_in[7];
    ptrs.src[2] = (const int*)d_in[11]; ptrs.dst[2] = (const int*)d_in[12]; ptrs.w[2] = (const float*)d_in[13];
    ptrs.src[3] = (const int*)d_in[2];  ptrs.dst[3] = (const int*)d_in[3];  ptrs.w[3] = (const float*)d_in[4];

    // ws layout (~150 MB of 256 MiB; no overlays)
    const int totalCnt = 4 * NB * GS;           // 160000
    char* p = (char*)d_ws;
    float* rdego       = (float*)p;  p += (size_t)4 * N * 4;
    int*   cnt_store   = (int*)p;    p += (size_t)totalCnt * 4;
    int*   scanex      = (int*)p;    p += (size_t)totalCnt * 4;
    int*   bsum        = (int*)p;    p += (size_t)1024 * 4;
    int*   cursor_base = (int*)p;    p += (size_t)totalCnt * 4;
    int*   bucket_ptr  = (int*)p;    p += (size_t)4 * (NB + 1) * 4;
    int*   row_ptr     = (int*)p;    p += (size_t)4 * (N + 1) * 4;
    ull*   csr8        = (ull*)p;    p += (size_t)4 * E * 8;               // 32 MB
    unsigned* csr2u    = (unsigned*)p; p += (size_t)4 * E * 4;             // 16 MB
    __half* h16com     = (__half*)p; p += (size_t)N * D * 2;               // 10.24 MB
    __half* h16pos     = (__half*)p; p += (size_t)N * D * 2;               // 10.24 MB
    __half* agg16      = (__half*)p; p += (size_t)4 * N * D * 2;           // 40.96 MB
    __half* wpack      = (__half*)p; p += (size_t)4 * 2048 * 8 * 2;        // 128 KB
    __half* histo16    = (__half*)p;                                       // 20.48 MB

    const int cBlocks = (N * D / 8 + 255) / 256;
    const int gBlocks = N / 4;                 // 1 wave per dst node
    const int sBlocks = (totalCnt + 1023) / 1024;

    conv_kernel<<<cBlocks, 256, 0, stream>>>(com_emb, h16com, N * D / 8);
    conv_kernel<<<cBlocks, 256, 0, stream>>>(pos_emb, h16pos, N * D / 8);
    wpack_kernel<<<32, 256, 0, stream>>>((const float*)d_in[18], (const float*)d_in[16],
                                         (const float*)d_in[20], (const float*)d_in[14],
                                         wpack);

    hist_kernel<<<4 * GS, 1024, 0, stream>>>(ptrs, histo16, cnt_store, E);
    reduce_kernel<<<(4 * N + 255) / 256, 256, 0, stream>>>(histo16, rdego, 4 * N);
    scan1_kernel<<<sBlocks, 1024, 0, stream>>>(cnt_store, scanex, bsum, totalCnt);
    scan2_kernel<<<1, 1024, 0, stream>>>(bsum, sBlocks);
    scan3_kernel<<<(totalCnt + 255) / 256, 256, 0, stream>>>(scanex, bsum, cursor_base,
                                                             bucket_ptr, totalCnt, E);

    fill4_kernel<<<4 * GS, 512, 0, stream>>>(ptrs, cursor_base, csr8, E);
    sort24_kernel<<<4 * NB, 256, 0, stream>>>(bucket_ptr, csr8, rdego, csr2u, row_ptr, E);
    gather4_kernel<<<4 * gBlocks, 256, 0, stream>>>(row_ptr, csr2u, h16com, h16pos,
                                                    agg16, gBlocks, E);

    // com half: A=supply(rel1), B=cflow(rel0); pos half: A=demand(rel3), B=pflow(rel2)
    projmf_kernel<<<N / 64, 256, 0, stream>>>(
        agg16 + (size_t)1 * N * D, wpack + (size_t)1 * 16384, (const float*)d_in[17],
        agg16 + (size_t)0 * N * D, wpack + (size_t)0 * 16384, (const float*)d_in[19],
        out_com);
    projmf_kernel<<<N / 64, 256, 0, stream>>>(
        agg16 + (size_t)3 * N * D, wpack + (size_t)3 * 16384, (const float*)d_in[15],
        agg16 + (size_t)2 * N * D, wpack + (size_t)2 * 16384, (const float*)d_in[21],
        out_pos);
}

// Round 16
// 310.218 us; speedup vs baseline: 1.5472x; 1.5472x over previous
//
#include <hip/hip_runtime.h>
#include <hip/hip_fp16.h>

#define D   128
#define NN  40000
#define NB  625      // dst buckets per relation (64 nodes each)
#define GS  64       // edge slices per relation (hist + fill)

typedef unsigned long long ull;
typedef __attribute__((ext_vector_type(8))) _Float16 f16x8;
typedef __attribute__((ext_vector_type(4))) float f32x4;

struct Ptrs { const int* src[4]; const int* dst[4]; const float* w[4]; };

// ---- convert f32 table -> fp16 interleaved [node][128] ---------------------
__global__ __launch_bounds__(256) void conv_kernel(
    const float* __restrict__ in, __half* __restrict__ out, int n8)
{
    int i = blockIdx.x * 256 + threadIdx.x;
    if (i >= n8) return;
    const float4* a = (const float4*)in + (size_t)i * 2;
    float4 v0 = a[0], v1 = a[1];
    __half2 pack[4];
    pack[0] = __floats2half2_rn(v0.x, v0.y);
    pack[1] = __floats2half2_rn(v0.z, v0.w);
    pack[2] = __floats2half2_rn(v1.x, v1.y);
    pack[3] = __floats2half2_rn(v1.z, v1.w);
    ((float4*)out)[i] = *(float4*)pack;
}

// ---- pack W [128][128] f32 -> per-fragment fp16 [kt(4)][ct(8)][lane(64)][8]
__global__ __launch_bounds__(256) void wpack_kernel(
    const float* __restrict__ W0, const float* __restrict__ W1,
    const float* __restrict__ W2, const float* __restrict__ W3,
    __half* __restrict__ wp)
{
    int t = blockIdx.x * 256 + threadIdx.x;   // rel*2048 + idx
    int rel = t >> 11;
    int idx = t & 2047;
    int lane = idx & 63;
    int ct = (idx >> 6) & 7;
    int kt = idx >> 9;
    const float* W = rel == 0 ? W0 : rel == 1 ? W1 : rel == 2 ? W2 : W3;
    int k0 = kt * 32 + (lane >> 4) * 8;
    int col = ct * 16 + (lane & 15);
    __half tmp[8];
#pragma unroll
    for (int j = 0; j < 8; ++j)
        tmp[j] = __float2half_rn(W[(size_t)(k0 + j) * D + col]);
    *(float4*)(wp + (size_t)t * 8) = *(float4*)tmp;
}

// ---- hist (fused bcnt): full-N LDS src histogram + dst bucket counts -------
__global__ __launch_bounds__(1024) void hist_kernel(
    Ptrs p, __half* __restrict__ histo16, int* __restrict__ cnt_store, int E)
{
    __shared__ float hist[NN];
    __shared__ int cnt[NB];
    const int bx  = blockIdx.x;         // rel*GS + rep
    const int rel = bx >> 6;
    const int rep = bx & (GS - 1);
    const int tid = threadIdx.x;

    for (int i = tid; i < NN; i += 1024) hist[i] = 0.f;
    for (int i = tid; i < NB; i += 1024) cnt[i] = 0;
    __syncthreads();

    const int es  = (E + GS - 1) / GS;
    const int beg = rep * es;
    const int end = min(beg + es, E);
    const int* srcp = p.src[rel];
    const int* dstp = p.dst[rel];
    const float* w = p.w[rel];
    for (int e = beg + tid; e < end; e += 1024) {
        atomicAdd(&hist[srcp[e]], w[e]);
        atomicAdd(&cnt[dstp[e] >> 6], 1);
    }
    __syncthreads();

    __half2* outp = (__half2*)(histo16 + (size_t)bx * NN);
    for (int i = tid; i < NN / 2; i += 1024)
        outp[i] = __floats2half2_rn(hist[2 * i], hist[2 * i + 1]);
    for (int b = tid; b < NB; b += 1024)
        cnt_store[((size_t)(rel * NB + b)) * GS + rep] = cnt[b];
}

__global__ __launch_bounds__(256) void reduce_kernel(
    const __half* __restrict__ histo16, float* __restrict__ rdego, int total)
{
    int i = blockIdx.x * 256 + threadIdx.x;     // i = rel*NN + node
    if (i >= total) return;
    int rel = i / NN;
    int node = i - rel * NN;
    const __half* bp = histo16 + (size_t)rel * GS * NN + node;
    float v = 0.f;
#pragma unroll
    for (int r = 0; r < GS; ++r) v += __half2float(bp[(size_t)r * NN]);
    rdego[i] = rsqrtf(v);
}

// ---- 3-kernel scan over 4*NB*GS = 160000 counts ----------------------------
__device__ inline int block_excl_scan(int v, int tid) {
    __shared__ int wsum[16];
    int lane = tid & 63, wid = tid >> 6;
    int x = v;
#pragma unroll
    for (int off = 1; off < 64; off <<= 1) {
        int y = __shfl_up(x, off, 64);
        if (lane >= off) x += y;
    }
    if (lane == 63) wsum[wid] = x;
    __syncthreads();
    if (wid == 0) {
        int y = (lane < 16) ? wsum[lane] : 0;
#pragma unroll
        for (int off = 1; off < 16; off <<= 1) {
            int t = __shfl_up(y, off, 64);
            if (lane >= off) y += t;
        }
        if (lane < 16) wsum[lane] = y;
    }
    __syncthreads();
    int woff = wid ? wsum[wid - 1] : 0;
    return woff + x - v;
}

__global__ __launch_bounds__(1024) void scan1_kernel(
    const int* __restrict__ cnt_store, int* __restrict__ scanex,
    int* __restrict__ bsum, int total)
{
    int tid = threadIdx.x;
    int i = blockIdx.x * 1024 + tid;
    int v = (i < total) ? cnt_store[i] : 0;
    int excl = block_excl_scan(v, tid);
    if (i < total) scanex[i] = excl;
    if (tid == 1023) bsum[blockIdx.x] = excl + v;
}

__global__ __launch_bounds__(1024) void scan2_kernel(int* __restrict__ bsum, int nb)
{
    int tid = threadIdx.x;
    int v = (tid < nb) ? bsum[tid] : 0;
    int excl = block_excl_scan(v, tid);
    if (tid < nb) bsum[tid] = excl;
}

__global__ __launch_bounds__(256) void scan3_kernel(
    const int* __restrict__ scanex, const int* __restrict__ bsum,
    int* __restrict__ cursor_base, int* __restrict__ bucket_ptr,
    int total, int E)
{
    int i = blockIdx.x * 256 + threadIdx.x;
    if (i >= total) return;
    int v = scanex[i] + bsum[i >> 10];
    int rel = i / (NB * GS);
    int rem = i - rel * (NB * GS);
    int b = rem / GS, rep = rem - b * GS;
    int local = v - rel * E;            // each relation has exactly E edges
    cursor_base[i] = local;
    if (rep == 0) bucket_ptr[rel * (NB + 1) + b] = local;
    if (rem == 0) bucket_ptr[rel * (NB + 1) + NB] = E;
}

// ---- fill4: all relations; coarse bucket sort; LDS cursors -----------------
__global__ __launch_bounds__(512) void fill4_kernel(
    Ptrs p, const int* __restrict__ cursor_base,
    ull* __restrict__ csr8, int E)
{
    __shared__ int lcur[NB];
    const int rel = blockIdx.x / GS;
    const int rep = blockIdx.x - rel * GS;
    const int tid = threadIdx.x;
    const int* cb = cursor_base + (size_t)rel * NB * GS;
    for (int b = tid; b < NB; b += 512)
        lcur[b] = cb[(size_t)b * GS + rep];
    __syncthreads();
    const int es  = (E + GS - 1) / GS;
    const int beg = rep * es;
    const int end = min(beg + es, E);
    const int* src = p.src[rel];
    const int* dst = p.dst[rel];
    const float* w = p.w[rel];
    ull* c8 = csr8 + (size_t)rel * E;
    for (int e = beg + tid; e < end; e += 512) {
        int s = src[e];
        int d = dst[e];
        int pos = atomicAdd(&lcur[d >> 6], 1);
        ull rec = (ull)(unsigned)(s | ((d & 63) << 16)) |
                  ((ull)__float_as_uint(w[e]) << 32);
        c8[pos] = rec;
    }
}

// ---- sort24: all relations; bucket -> exact per-dst CSR; bake wn; 4B recs --
__global__ __launch_bounds__(256) void sort24_kernel(
    const int* __restrict__ bucket_ptr, const ull* __restrict__ csr8,
    const float* __restrict__ rdego, unsigned* __restrict__ csr2u,
    int* __restrict__ row_ptr, int E)
{
    __shared__ int cnt[64];
    __shared__ int cur[64];
    __shared__ float swsum[64];
    const int rel = blockIdx.x / NB;
    const int b   = blockIdx.x - rel * NB;
    const int tid = threadIdx.x;
    const int* bp_r = bucket_ptr + rel * (NB + 1);
    const ull* c8 = csr8 + (size_t)rel * E;
    unsigned* c2 = csr2u + (size_t)rel * E;
    int* rp_r = row_ptr + rel * (NN + 1);
    const float* rd = rdego + (size_t)rel * NN;
    const int beg = bp_r[b];
    const int end = bp_r[b + 1];
    if (tid < 64) { cnt[tid] = 0; swsum[tid] = 0.f; }
    __syncthreads();
    for (int e = beg + tid; e < end; e += 256) {
        ull rec = c8[e];
        int j = (int)((rec >> 16) & 63);
        atomicAdd(&cnt[j], 1);
        atomicAdd(&swsum[j], __uint_as_float((unsigned)(rec >> 32)));
    }
    __syncthreads();
    if (tid < 64) {                      // wave 0: exclusive scan of 64 bins
        int v = cnt[tid];
        int x = v;
#pragma unroll
        for (int off = 1; off < 64; off <<= 1) {
            int y = __shfl_up(x, off, 64);
            if (tid >= off) x += y;
        }
        int start = beg + x - v;
        cur[tid] = start;
        rp_r[b * 64 + tid] = start;
        swsum[tid] = rsqrtf(swsum[tid]);
        if (b == 0 && tid == 0) rp_r[NN] = E;
    }
    __syncthreads();
    for (int e = beg + tid; e < end; e += 256) {
        ull rec = c8[e];
        int j = (int)((rec >> 16) & 63);
        int s = (int)(rec & 0xFFFF);
        float wn = __uint_as_float((unsigned)(rec >> 32)) * rd[s] * swsum[j];
        int pos = atomicAdd(&cur[j], 1);
        c2[pos] = (unsigned)s |
                  ((unsigned)__half_as_ushort(__float2half_rn(wn)) << 16);
    }
}

// ---- gather4: all relations; one wave/node; MLP=8 (2-deep unroll x 4 grp) --
__global__ __launch_bounds__(256) void gather4_kernel(
    const int* __restrict__ row_ptr, const unsigned* __restrict__ csr2u,
    const __half* __restrict__ h16com, const __half* __restrict__ h16pos,
    __half* __restrict__ agg16, int gBlocks, int E)
{
    int rel = blockIdx.x / gBlocks;
    int lb  = blockIdx.x - rel * gBlocks;
    int node = (lb * 256 + threadIdx.x) >> 6;
    int lane = threadIdx.x & 63;
    if (node >= NN) return;
    const int* rp = row_ptr + rel * (NN + 1);
    const unsigned* c2 = csr2u + (size_t)rel * E;
    const __half* h16 = (rel == 0 || rel == 3) ? h16com : h16pos;
    __half* agg = agg16 + (size_t)rel * NN * D;

    int beg = rp[node], end = rp[node + 1];
    const int g = lane >> 4, l16 = lane & 15;

    float acc[8] = {};
    int e = beg;
    // 2-deep unrolled: 8 rows in flight per wave
    for (; e + 8 <= end; e += 8) {
        unsigned rec0 = __builtin_nontemporal_load(c2 + e + g);
        unsigned rec1 = __builtin_nontemporal_load(c2 + e + 4 + g);
        int s0 = (int)(rec0 & 0xFFFF);
        int s1 = (int)(rec1 & 0xFFFF);
        f32x4 hv0 = ((const f32x4*)(h16 + (size_t)s0 * D))[l16];
        f32x4 hv1 = ((const f32x4*)(h16 + (size_t)s1 * D))[l16];
        float wn0 = __half2float(__ushort_as_half((unsigned short)(rec0 >> 16)));
        float wn1 = __half2float(__ushort_as_half((unsigned short)(rec1 >> 16)));
        __half2* hp0 = (__half2*)&hv0;
        __half2* hp1 = (__half2*)&hv1;
#pragma unroll
        for (int k = 0; k < 4; ++k) {
            float2 f0 = __half22float2(hp0[k]);
            float2 f1 = __half22float2(hp1[k]);
            acc[2 * k]     += wn0 * f0.x + wn1 * f1.x;
            acc[2 * k + 1] += wn0 * f0.y + wn1 * f1.y;
        }
    }
    // tail: 4-at-a-time with predication
    for (; e < end; e += 4) {
        int ee = e + g;
        int valid = ee < end;
        unsigned rec = __builtin_nontemporal_load(c2 + (valid ? ee : (end - 1)));
        int s = (int)(rec & 0xFFFF);
        float wn = valid ? __half2float(__ushort_as_half((unsigned short)(rec >> 16))) : 0.f;
        f32x4 hv4 = ((const f32x4*)(h16 + (size_t)s * D))[l16];
        __half2* hp = (__half2*)&hv4;
#pragma unroll
        for (int k = 0; k < 4; ++k) {
            float2 f = __half22float2(hp[k]);
            acc[2 * k]     += wn * f.x;
            acc[2 * k + 1] += wn * f.y;
        }
    }
#pragma unroll
    for (int k = 0; k < 8; ++k) {
        acc[k] += __shfl_xor(acc[k], 16, 64);
        acc[k] += __shfl_xor(acc[k], 32, 64);
    }
    if (g == 0) {
        __half2 pack[4];
        pack[0] = __floats2half2_rn(acc[0], acc[1]);
        pack[1] = __floats2half2_rn(acc[2], acc[3]);
        pack[2] = __floats2half2_rn(acc[4], acc[5]);
        pack[3] = __floats2half2_rn(acc[6], acc[7]);
        __builtin_nontemporal_store(*(f32x4*)pack,
                                    (f32x4*)(agg + (size_t)node * D) + l16);
    }
}

// ---- projmf: MFMA fp16 GEMM, both relations of an output half fused --------
__global__ __launch_bounds__(256) void projmf_kernel(
    const __half* __restrict__ aggA, const __half* __restrict__ wpA,
    const float* __restrict__ bA,
    const __half* __restrict__ aggB, const __half* __restrict__ wpB,
    const float* __restrict__ bB, float* __restrict__ outh)
{
    __shared__ char As[2][64 * 256];    // 2 x 16 KB, XOR-swizzled rows
    const int t = threadIdx.x;
    const int row0 = blockIdx.x * 64;

    for (int r2 = 0; r2 < 2; ++r2) {
        const float4* src = (const float4*)((r2 ? aggB : aggA) + (size_t)row0 * D);
        for (int i = t; i < 1024; i += 256) {
            int row = i >> 4, ch = i & 15;
            int byte = row * 256 + ch * 16;
            byte ^= (row & 7) << 4;
            *(float4*)(As[r2] + byte) = src[i];
        }
    }
    __syncthreads();

    const int wv = t >> 6, lane = t & 63;
    const int rbase = wv * 16;

    f16x8 aA[4], aB[4];
#pragma unroll
    for (int kt = 0; kt < 4; ++kt) {
        int row = rbase + (lane & 15);
        int byte = row * 256 + kt * 64 + (lane >> 4) * 16;
        byte ^= (row & 7) << 4;
        aA[kt] = *(const f16x8*)(As[0] + byte);
        aB[kt] = *(const f16x8*)(As[1] + byte);
    }

    f32x4 accA[8], accB[8];
#pragma unroll
    for (int i = 0; i < 8; ++i) {
        accA[i] = (f32x4){0.f, 0.f, 0.f, 0.f};
        accB[i] = (f32x4){0.f, 0.f, 0.f, 0.f};
    }

#pragma unroll
    for (int ct = 0; ct < 8; ++ct) {
#pragma unroll
        for (int kt = 0; kt < 4; ++kt) {
            f16x8 bfA = *(const f16x8*)(wpA + ((size_t)((kt * 8 + ct) * 64 + lane)) * 8);
            f16x8 bfB = *(const f16x8*)(wpB + ((size_t)((kt * 8 + ct) * 64 + lane)) * 8);
            accA[ct] = __builtin_amdgcn_mfma_f32_16x16x32_f16(aA[kt], bfA, accA[ct], 0, 0, 0);
            accB[ct] = __builtin_amdgcn_mfma_f32_16x16x32_f16(aB[kt], bfB, accB[ct], 0, 0, 0);
        }
    }

    // C/D layout: col = lane&15, row = (lane>>4)*4 + v
#pragma unroll
    for (int ct = 0; ct < 8; ++ct) {
        int col = ct * 16 + (lane & 15);
        float ba = bA[col], bb = bB[col];
#pragma unroll
        for (int v = 0; v < 4; ++v) {
            int row = row0 + rbase + (lane >> 4) * 4 + v;
            float r = 0.5f * (fmaxf(accA[ct][v] + ba, 0.f) +
                              fmaxf(accB[ct][v] + bb, 0.f));
            outh[(size_t)row * D + col] = r;
        }
    }
}

extern "C" void kernel_launch(void* const* d_in, const int* in_sizes, int n_in,
                              void* d_out, int out_size, void* d_ws, size_t ws_size,
                              hipStream_t stream) {
    const float* com_emb = (const float*)d_in[0];
    const float* pos_emb = (const float*)d_in[1];
    const int E = in_sizes[2];       // 1,000,000
    const int N = NN;

    float* out = (float*)d_out;
    float* out_com = out;
    float* out_pos = out + (size_t)N * D;

    // relation order: 0=cflow(com->com) 1=supply(pos->com) 2=pflow(pos->pos) 3=demand(com->pos)
    Ptrs ptrs;
    ptrs.src[0] = (const int*)d_in[8];  ptrs.dst[0] = (const int*)d_in[9];  ptrs.w[0] = (const float*)d_in[10];
    ptrs.src[1] = (const int*)d_in[5];  ptrs.dst[1] = (const int*)d_in[6];  ptrs.w[1] = (const float*)d_in[7];
    ptrs.src[2] = (const int*)d_in[11]; ptrs.dst[2] = (const int*)d_in[12]; ptrs.w[2] = (const float*)d_in[13];
    ptrs.src[3] = (const int*)d_in[2];  ptrs.dst[3] = (const int*)d_in[3];  ptrs.w[3] = (const float*)d_in[4];

    // ws layout (~150 MB of 256 MiB; no overlays)
    const int totalCnt = 4 * NB * GS;           // 160000
    char* p = (char*)d_ws;
    float* rdego       = (float*)p;  p += (size_t)4 * N * 4;
    int*   cnt_store   = (int*)p;    p += (size_t)totalCnt * 4;
    int*   scanex      = (int*)p;    p += (size_t)totalCnt * 4;
    int*   bsum        = (int*)p;    p += (size_t)1024 * 4;
    int*   cursor_base = (int*)p;    p += (size_t)totalCnt * 4;
    int*   bucket_ptr  = (int*)p;    p += (size_t)4 * (NB + 1) * 4;
    int*   row_ptr     = (int*)p;    p += (size_t)4 * (N + 1) * 4;
    ull*   csr8        = (ull*)p;    p += (size_t)4 * E * 8;               // 32 MB
    unsigned* csr2u    = (unsigned*)p; p += (size_t)4 * E * 4;             // 16 MB
    __half* h16com     = (__half*)p; p += (size_t)N * D * 2;               // 10.24 MB
    __half* h16pos     = (__half*)p; p += (size_t)N * D * 2;               // 10.24 MB
    __half* agg16      = (__half*)p; p += (size_t)4 * N * D * 2;           // 40.96 MB
    __half* wpack      = (__half*)p; p += (size_t)4 * 2048 * 8 * 2;        // 128 KB
    __half* histo16    = (__half*)p;                                       // 20.48 MB

    const int cBlocks = (N * D / 8 + 255) / 256;
    const int gBlocks = N / 4;                 // 1 wave per dst node
    const int sBlocks = (totalCnt + 1023) / 1024;

    conv_kernel<<<cBlocks, 256, 0, stream>>>(com_emb, h16com, N * D / 8);
    conv_kernel<<<cBlocks, 256, 0, stream>>>(pos_emb, h16pos, N * D / 8);
    wpack_kernel<<<32, 256, 0, stream>>>((const float*)d_in[18], (const float*)d_in[16],
                                         (const float*)d_in[20], (const float*)d_in[14],
                                         wpack);

    hist_kernel<<<4 * GS, 1024, 0, stream>>>(ptrs, histo16, cnt_store, E);
    reduce_kernel<<<(4 * N + 255) / 256, 256, 0, stream>>>(histo16, rdego, 4 * N);
    scan1_kernel<<<sBlocks, 1024, 0, stream>>>(cnt_store, scanex, bsum, totalCnt);
    scan2_kernel<<<1, 1024, 0, stream>>>(bsum, sBlocks);
    scan3_kernel<<<(totalCnt + 255) / 256, 256, 0, stream>>>(scanex, bsum, cursor_base,
                                                             bucket_ptr, totalCnt, E);

    fill4_kernel<<<4 * GS, 512, 0, stream>>>(ptrs, cursor_base, csr8, E);
    sort24_kernel<<<4 * NB, 256, 0, stream>>>(bucket_ptr, csr8, rdego, csr2u, row_ptr, E);
    gather4_kernel<<<4 * gBlocks, 256, 0, stream>>>(row_ptr, csr2u, h16com, h16pos,
                                                    agg16, gBlocks, E);

    // com half: A=supply(rel1), B=cflow(rel0); pos half: A=demand(rel3), B=pflow(rel2)
    projmf_kernel<<<N / 64, 256, 0, stream>>>(
        agg16 + (size_t)1 * N * D, wpack + (size_t)1 * 16384, (const float*)d_in[17],
        agg16 + (size_t)0 * N * D, wpack + (size_t)0 * 16384, (const float*)d_in[19],
        out_com);
    projmf_kernel<<<N / 64, 256, 0, stream>>>(
        agg16 + (size_t)3 * N * D, wpack + (size_t)3 * 16384, (const float*)d_in[15],
        agg16 + (size_t)2 * N * D, wpack + (size_t)2 * 16384, (const float*)d_in[21],
        out_pos);
}